// Round 7
// baseline (395.844 us; speedup 1.0000x reference)
//
#include <hip/hip_runtime.h>
#include <hip/hip_bf16.h>
#include <cstdint>
#include <cstddef>

// B=4, S=2048, D=1024, H=16, DK=64. Device I/O dtype: FLOAT32.
// Internal compute: bf16 MFMA with f32 accumulation.
static constexpr int kB = 4, kS = 2048, kD = 1024, kH = 16, kDK = 64;
static constexpr int kM = kB * kS;

typedef __attribute__((ext_vector_type(8))) __bf16 bf16x8;
typedef __attribute__((ext_vector_type(4))) float f32x4;

#define MFMA_BF16(a, b, c) __builtin_amdgcn_mfma_f32_16x16x32_bf16((a), (b), (c), 0, 0, 0)

#define GLDS16(gp, lp)                                                        \
  __builtin_amdgcn_global_load_lds(                                           \
      (__attribute__((address_space(1))) void*)(gp),                          \
      (__attribute__((address_space(3))) void*)(lp), 16, 0, 0)

// ---------------------------------------------------------------------------
// f32 -> bf16 helpers
// ---------------------------------------------------------------------------
__device__ __forceinline__ bf16x8 to8(const float4& a, const float4& b) {
  bf16x8 o;
  o[0] = (__bf16)a.x; o[1] = (__bf16)a.y; o[2] = (__bf16)a.z; o[3] = (__bf16)a.w;
  o[4] = (__bf16)b.x; o[5] = (__bf16)b.y; o[6] = (__bf16)b.z; o[7] = (__bf16)b.w;
  return o;
}

__device__ __forceinline__ bf16x8 cvt8(const float* s, int i) {
  const float4 a = ((const float4*)s)[i * 2 + 0];
  const float4 b = ((const float4*)s)[i * 2 + 1];
  return to8(a, b);
}

__global__ __launch_bounds__(256) void cvt_f32_bf16(
    const float* __restrict__ src, __bf16* __restrict__ dst, int n8) {
  const int i = blockIdx.x * 256 + threadIdx.x;
  if (i >= n8) return;
  ((bf16x8*)dst)[i] = cvt8(src, i);
}

// ---------------------------------------------------------------------------
// Fused GEMM core, f32 inputs: C[M,N] = A[M,K]*W[N,K]^T + bias.
// 128x128 tile, BK=64, XOR-granule LDS swizzle (round-0 proven geometry).
// Conversion fused in. A/W are f32; each thread reg-stages 8+8 float4 per
// K-step (T14 async-split):
//   loop top: cvt regs (k0) -> ds_write          [compiler waits vmcnt per-use]
//             lgkmcnt(0); s_barrier              [writes visible; NO vmcnt drain
//                                                 -- global loads target regs,
//                                                 no cross-wave hazard]
//             issue f32 loads (k0+64)            [hide under MFMA cluster]
//             MFMA phase (ds_read frags)
//             s_barrier                          [reads done -> overwrite safe]
// Removes the cvt kernel, its 150 MB traffic, and the GLDS vmcnt(0) drain.
// mode 0: out[m*1024+n] ; mode 1: [b][h][s][dk] ; mode 2: [b][h][dk][s]
// ---------------------------------------------------------------------------
template <typename OutT>
__device__ __forceinline__ void gemm_core_f(
    const float* __restrict__ A, const float* __restrict__ W,
    const float* __restrict__ bias, OutT* __restrict__ out, int mode, int bid,
    __bf16* As, __bf16* Ws) {
  const int tid = threadIdx.x;
  const int wave = tid >> 6, lane = tid & 63;
  const int col = lane & 15, quad = lane >> 4;
  const int m0 = (bid & 63) * 128;
  const int n0 = (bid >> 6) * 128;
  const int wr = (wave & 1) * 64, wc = (wave >> 1) * 64;

  f32x4 acc[4][4] = {};

  // staging geometry: slot s = i*256+tid -> row s>>3, LDS granule s&7 holds
  // global granule (s&7)^(row&7); LDS dest byte = i*4096 + tid*16 (linear).
  int srow[4], sgo[4];
#pragma unroll
  for (int i = 0; i < 4; ++i) {
    const int s = i * 256 + tid;
    srow[i] = s >> 3;
    sgo[i] = ((s & 7) ^ ((s >> 3) & 7)) * 8;
  }
  const int g0 = ((quad) ^ (col & 7)) * 16;
  const int g1 = ((quad + 4) ^ (col & 7)) * 16;

  float4 ra[4][2], rw[4][2];

  auto issue = [&](int k0) {
#pragma unroll
    for (int i = 0; i < 4; ++i) {
      const float4* pa =
          (const float4*)(A + (size_t)(m0 + srow[i]) * 1024 + k0 + sgo[i]);
      const float4* pw =
          (const float4*)(W + (size_t)(n0 + srow[i]) * 1024 + k0 + sgo[i]);
      ra[i][0] = pa[0];
      ra[i][1] = pa[1];
      rw[i][0] = pw[0];
      rw[i][1] = pw[1];
    }
  };

  issue(0);
  for (int k0 = 0; k0 < 1024; k0 += 64) {
    // write phase: cvt staged regs -> LDS (compiler inserts per-use vmcnt)
#pragma unroll
    for (int i = 0; i < 4; ++i) {
      *(bf16x8*)((char*)As + i * 4096 + tid * 16) = to8(ra[i][0], ra[i][1]);
      *(bf16x8*)((char*)Ws + i * 4096 + tid * 16) = to8(rw[i][0], rw[i][1]);
    }
    asm volatile("s_waitcnt lgkmcnt(0)" ::: "memory");
    __builtin_amdgcn_s_barrier();
    asm volatile("" ::: "memory");

    if (k0 < 960) issue(k0 + 64);  // T14: latency hidden under MFMA cluster

#pragma unroll
    for (int h = 0; h < 2; ++h) {
      const int go = h ? g1 : g0;
      bf16x8 af[4], wf[4];
#pragma unroll
      for (int t = 0; t < 4; ++t) {
        af[t] = *(const bf16x8*)((const char*)As + (wr + t * 16 + col) * 128 + go);
        wf[t] = *(const bf16x8*)((const char*)Ws + (wc + t * 16 + col) * 128 + go);
      }
#pragma unroll
      for (int rt = 0; rt < 4; ++rt)
#pragma unroll
        for (int ct = 0; ct < 4; ++ct)
          acc[rt][ct] = MFMA_BF16(af[rt], wf[ct], acc[rt][ct]);
    }
    __builtin_amdgcn_s_barrier();  // all waves done reading -> overwrite safe
    asm volatile("" ::: "memory");
  }

#pragma unroll
  for (int ct = 0; ct < 4; ++ct) {
    const int n = n0 + wc + ct * 16 + col;
    const float bb = bias[n];
#pragma unroll
    for (int rt = 0; rt < 4; ++rt) {
#pragma unroll
      for (int r = 0; r < 4; ++r) {
        const int m = m0 + wr + rt * 16 + quad * 4 + r;
        const float v = acc[rt][ct][r] + bb;
        size_t idx;
        if (mode == 0) {
          idx = (size_t)m * 1024 + n;
        } else {
          const int b = m >> 11, s = m & 2047;
          const int h = n >> 6, dk = n & 63;
          if (mode == 1)
            idx = ((size_t)(b * 16 + h) * 2048 + s) * 64 + dk;
          else
            idx = ((size_t)(b * 16 + h) * 64 + dk) * 2048 + s;
        }
        out[idx] = (OutT)v;
      }
    }
  }
}

// Q/K/V projections from f32 inputs, one 1536-block launch
__global__ __launch_bounds__(256, 2) void gemm_qkv_f(
    const float* __restrict__ Aq, const float* __restrict__ Ak,
    const float* __restrict__ Av, const float* __restrict__ Wq,
    const float* __restrict__ Wk, const float* __restrict__ Wv,
    const float* __restrict__ bq, const float* __restrict__ bk,
    const float* __restrict__ bv, __bf16* __restrict__ Qw,
    __bf16* __restrict__ Kw, __bf16* __restrict__ Vw) {
  __shared__ __align__(16) __bf16 As[128 * 64];
  __shared__ __align__(16) __bf16 Ws[128 * 64];
  const int seg = blockIdx.x >> 9;
  const int bid = blockIdx.x & 511;
  const float* A = seg == 0 ? Aq : seg == 1 ? Ak : Av;
  const float* W = seg == 0 ? Wq : seg == 1 ? Wk : Wv;
  const float* bias = seg == 0 ? bq : seg == 1 ? bk : bv;
  __bf16* out = seg == 0 ? Qw : seg == 1 ? Kw : Vw;
  gemm_core_f<__bf16>(A, W, bias, out, seg == 2 ? 2 : 1, bid, As, Ws);
}

// out-projection from f32 ctx + f32 Wo
__global__ __launch_bounds__(256, 2) void gemm_out_f(
    const float* __restrict__ A, const float* __restrict__ W,
    const float* __restrict__ bias, float* __restrict__ out) {
  __shared__ __align__(16) __bf16 As[128 * 64];
  __shared__ __align__(16) __bf16 Ws[128 * 64];
  gemm_core_f<float>(A, W, bias, out, 0, blockIdx.x, As, Ws);
}

// ---------------------------------------------------------------------------
// Legacy bf16 GEMM core (fallback path only).
// ---------------------------------------------------------------------------
template <typename OutT>
__device__ __forceinline__ void gemm_core(
    const __bf16* __restrict__ A, const __bf16* __restrict__ W,
    const float* __restrict__ bias, OutT* __restrict__ out, int mode, int bid,
    __bf16* As, __bf16* Ws) {
  const int tid = threadIdx.x;
  const int wave = tid >> 6, lane = tid & 63;
  const int col = lane & 15, quad = lane >> 4;
  const int m0 = (bid & 63) * 128;
  const int n0 = (bid >> 6) * 128;
  const int wr = (wave & 1) * 64, wc = (wave >> 1) * 64;

  f32x4 acc[4][4] = {};

  int srow[4], sgo[4];
#pragma unroll
  for (int i = 0; i < 4; ++i) {
    const int s = i * 256 + tid;
    srow[i] = s >> 3;
    sgo[i] = (((s & 7) ^ ((s >> 3) & 7))) * 8;
  }
  const int g0 = ((quad) ^ (col & 7)) * 16;
  const int g1 = ((quad + 4) ^ (col & 7)) * 16;

  for (int k0 = 0; k0 < 1024; k0 += 64) {
#pragma unroll
    for (int i = 0; i < 4; ++i) {
      GLDS16(A + (size_t)(m0 + srow[i]) * 1024 + k0 + sgo[i],
             (char*)As + i * 4096 + wave * 1024);
      GLDS16(W + (size_t)(n0 + srow[i]) * 1024 + k0 + sgo[i],
             (char*)Ws + i * 4096 + wave * 1024);
    }
    __syncthreads();
#pragma unroll
    for (int h = 0; h < 2; ++h) {
      const int go = h ? g1 : g0;
      bf16x8 af[4], wf[4];
#pragma unroll
      for (int t = 0; t < 4; ++t) {
        af[t] = *(const bf16x8*)((const char*)As + (wr + t * 16 + col) * 128 + go);
        wf[t] = *(const bf16x8*)((const char*)Ws + (wc + t * 16 + col) * 128 + go);
      }
#pragma unroll
      for (int rt = 0; rt < 4; ++rt)
#pragma unroll
        for (int ct = 0; ct < 4; ++ct)
          acc[rt][ct] = MFMA_BF16(af[rt], wf[ct], acc[rt][ct]);
    }
    __syncthreads();
  }

#pragma unroll
  for (int ct = 0; ct < 4; ++ct) {
    const int n = n0 + wc + ct * 16 + col;
    const float bb = bias[n];
#pragma unroll
    for (int rt = 0; rt < 4; ++rt) {
#pragma unroll
      for (int r = 0; r < 4; ++r) {
        const int m = m0 + wr + rt * 16 + quad * 4 + r;
        const float v = acc[rt][ct][r] + bb;
        size_t idx;
        if (mode == 0) {
          idx = (size_t)m * 1024 + n;
        } else {
          const int b = m >> 11, s = m & 2047;
          const int h = n >> 6, dk = n & 63;
          if (mode == 1)
            idx = ((size_t)(b * 16 + h) * 2048 + s) * 64 + dk;
          else
            idx = ((size_t)(b * 16 + h) * 64 + dk) * 2048 + s;
        }
        out[idx] = (OutT)v;
      }
    }
  }
}

template <int MODE, typename OutT>
__global__ __launch_bounds__(256) void gemm_one(
    const __bf16* __restrict__ A, const __bf16* __restrict__ W,
    const float* __restrict__ bias, OutT* __restrict__ out) {
  __shared__ __align__(16) __bf16 As[128 * 64];
  __shared__ __align__(16) __bf16 Ws[128 * 64];
  gemm_core<OutT>(A, W, bias, out, MODE, blockIdx.x, As, Ws);
}

// ---------------------------------------------------------------------------
// Causal flash attention (round-5 verified structure; output type templated).
// Single K/V buffers, counted-vmcnt split staging:
//   entry: vmcnt(2) [K(c) landed]; barrier; QK; barrier -> stage K(c+1);
//   exp/P; vmcnt(2) [V(c) landed]; barrier; PV; barrier -> stage V(c+1).
// LDS 34816 -> 4 blocks/CU; pair-major block order for XCD L2 locality.
// ---------------------------------------------------------------------------
template <typename CtxT>
__global__ __launch_bounds__(256, 4) void flash_attn(
    const __bf16* __restrict__ Q, const __bf16* __restrict__ K,
    const __bf16* __restrict__ Vt, CtxT* __restrict__ ctx) {
  __shared__ __align__(16) __bf16 Ks[64 * 64];
  __shared__ __align__(16) __bf16 Vs[64 * 64];
  __shared__ __align__(16) __bf16 Pb[4][2][16 * 72];

  const int tid = threadIdx.x;
  const int wave = tid >> 6, lane = tid & 63;
  const int col = lane & 15, quad = lane >> 4;
  const int bh = blockIdx.x & 63;    // pair-major order
  const int pair = blockIdx.x >> 6;
  const int b = bh >> 4, h = bh & 15;
  const int t_lo = pair, t_hi = 31 - pair;
  const int q0f[2] = {t_lo * 64 + wave * 16, t_hi * 64 + wave * 16};

  constexpr float SCL = 0.18033688011112042f;  // (1/8) * log2(e)

  bf16x8 qf[2][2];
#pragma unroll
  for (int f = 0; f < 2; ++f) {
    const __bf16* Qp = Q + ((size_t)bh * kS + q0f[f] + col) * 64 + quad * 8;
    qf[f][0] = *(const bf16x8*)Qp;
    qf[f][1] = *(const bf16x8*)(Qp + 32);
  }

  f32x4 o[2][4] = {};
  f32x4 lacc[2] = {};
  bf16x8 ones;
#pragma unroll
  for (int i = 0; i < 8; ++i) ones[i] = (__bf16)1.0f;

  const __bf16* Kg = K + (size_t)bh * kS * 64;
  const __bf16* Vg = Vt + (size_t)bh * 64 * kS;

  const int row0 = tid >> 3, g0 = (tid & 7) ^ (row0 & 7);
  const int row1 = (256 + tid) >> 3, g1 = (tid & 7) ^ (row1 & 7);

  const int fgoff0 = ((quad) ^ (col & 7)) * 16;
  const int fgoff1 = ((quad + 4) ^ (col & 7)) * 16;
  const int maskbase = wave * 16 + quad * 4;

  __bf16* Pw0 = &Pb[wave][0][0];
  __bf16* Pw1 = &Pb[wave][1][0];
  const __bf16* Pr0 = Pw0 + col * 72 + quad * 8;
  const __bf16* Pr1 = Pw1 + col * 72 + quad * 8;

  auto stageK = [&](int c) {
    char* KsB = (char*)Ks + wave * 1024;
    GLDS16(Kg + (size_t)(c * 64 + row0) * 64 + g0 * 8, KsB);
    GLDS16(Kg + (size_t)(c * 64 + row1) * 64 + g1 * 8, KsB + 4096);
  };
  auto stageV = [&](int c) {
    char* VsB = (char*)Vs + wave * 1024;
    GLDS16(Vg + (size_t)row0 * kS + c * 64 + g0 * 8, VsB);
    GLDS16(Vg + (size_t)row1 * kS + c * 64 + g1 * 8, VsB + 4096);
  };

  auto body = [&](int c, bool lo, bool d0, bool d1, bool stage_next) {
    asm volatile("s_waitcnt vmcnt(2)" ::: "memory");  // K(c) landed
    __builtin_amdgcn_s_barrier();
    asm volatile("" ::: "memory");

    f32x4 s[2][4];
#pragma unroll
    for (int kt = 0; kt < 4; ++kt) {
      const char* kp = (const char*)Ks + (kt * 16 + col) * 128;
      const bf16x8 kf0 = *(const bf16x8*)(kp + fgoff0);
      const bf16x8 kf1 = *(const bf16x8*)(kp + fgoff1);
      f32x4 z = {};
      s[1][kt] = MFMA_BF16(qf[1][1], kf1, MFMA_BF16(qf[1][0], kf0, z));
      if (lo) s[0][kt] = MFMA_BF16(qf[0][1], kf1, MFMA_BF16(qf[0][0], kf0, z));
    }

    __builtin_amdgcn_s_barrier();  // K WAR: all waves done reading Ks
    asm volatile("" ::: "memory");
    if (stage_next) stageK(c + 1);

#pragma unroll
    for (int kt = 0; kt < 4; ++kt) {
#pragma unroll
      for (int r = 0; r < 4; ++r) {
        float pv1 = __builtin_amdgcn_exp2f(s[1][kt][r] * SCL);
        if (d1 && (kt * 16 + col > maskbase + r)) pv1 = 0.0f;
        Pw1[(quad * 4 + r) * 72 + kt * 16 + col] = (__bf16)pv1;
        if (lo) {
          float pv0 = __builtin_amdgcn_exp2f(s[0][kt][r] * SCL);
          if (d0 && (kt * 16 + col > maskbase + r)) pv0 = 0.0f;
          Pw0[(quad * 4 + r) * 72 + kt * 16 + col] = (__bf16)pv0;
        }
      }
    }
    __threadfence_block();

    if (stage_next)
      asm volatile("s_waitcnt vmcnt(2)" ::: "memory");  // V(c) landed
    else
      asm volatile("s_waitcnt vmcnt(0)" ::: "memory");
    __builtin_amdgcn_s_barrier();
    asm volatile("" ::: "memory");

    const bf16x8 pf1a = *(const bf16x8*)Pr1;
    const bf16x8 pf1b = *(const bf16x8*)(Pr1 + 32);
    bf16x8 pf0a = {}, pf0b = {};
    if (lo) {
      pf0a = *(const bf16x8*)Pr0;
      pf0b = *(const bf16x8*)(Pr0 + 32);
    }
#pragma unroll
    for (int dt = 0; dt < 4; ++dt) {
      const char* vp = (const char*)Vs + (dt * 16 + col) * 128;
      const bf16x8 vf0 = *(const bf16x8*)(vp + fgoff0);
      const bf16x8 vf1 = *(const bf16x8*)(vp + fgoff1);
      o[1][dt] = MFMA_BF16(pf1b, vf1, MFMA_BF16(pf1a, vf0, o[1][dt]));
      if (lo) o[0][dt] = MFMA_BF16(pf0b, vf1, MFMA_BF16(pf0a, vf0, o[0][dt]));
    }
    lacc[1] = MFMA_BF16(pf1b, ones, MFMA_BF16(pf1a, ones, lacc[1]));
    if (lo) lacc[0] = MFMA_BF16(pf0b, ones, MFMA_BF16(pf0a, ones, lacc[0]));

    __builtin_amdgcn_s_barrier();  // V WAR: all waves done reading Vs
    asm volatile("" ::: "memory");
    if (stage_next) stageV(c + 1);
  };

  stageK(0);
  stageV(0);
  for (int c = 0; c <= t_lo; ++c) body(c, true, c == t_lo, false, c < t_hi);
  for (int c = t_lo + 1; c <= t_hi; ++c)
    body(c, false, false, c == t_hi, c < t_hi);

#pragma unroll
  for (int f = 0; f < 2; ++f) {
#pragma unroll
    for (int r = 0; r < 4; ++r) {
      const float inv = 1.0f / lacc[f][r];
      const int srow = q0f[f] + quad * 4 + r;
      CtxT* cp = ctx + ((size_t)b * kS + srow) * kD + h * 64 + col;
#pragma unroll
      for (int dt = 0; dt < 4; ++dt)
        cp[dt * 16] = (CtxT)(o[f][dt][r] * inv);
    }
  }
}

// ---------------------------------------------------------------------------
extern "C" void kernel_launch(void* const* d_in, const int* in_sizes, int n_in,
                              void* d_out, int out_size, void* d_ws, size_t ws_size,
                              hipStream_t stream) {
  const float* query = (const float*)d_in[0];
  const float* key_  = (const float*)d_in[1];
  const float* value = (const float*)d_in[2];
  const float* Wq = (const float*)d_in[4];
  const float* bq = (const float*)d_in[5];
  const float* Wk = (const float*)d_in[6];
  const float* bk = (const float*)d_in[7];
  const float* Wv = (const float*)d_in[8];
  const float* bv = (const float*)d_in[9];
  const float* Wo = (const float*)d_in[10];
  const float* bo = (const float*)d_in[11];

  const size_t e = (size_t)kM * kD;       // 8,388,608
  const size_t w = (size_t)kD * kD;       // 1,048,576
  float* out = (float*)d_out;

  // fused path: Qw,Kw,Vw bf16 + ctx f32 = 10e bytes (~84 MB)
  const size_t REQ = 3 * e * sizeof(__bf16) + e * sizeof(float);

  if (ws_size >= REQ) {
    __bf16* Qw = (__bf16*)d_ws;
    __bf16* Kw = Qw + e;
    __bf16* Vw = Kw + e;                  // [B,H,64,S]
    float* Ctx = (float*)(Vw + e);        // [B,S,D] f32

    gemm_qkv_f<<<1536, 256, 0, stream>>>(query, key_, value, Wq, Wk, Wv,
                                         bq, bk, bv, Qw, Kw, Vw);
    flash_attn<float><<<kB * kH * 16, 256, 0, stream>>>(Qw, Kw, Vw, Ctx);
    gemm_out_f<<<512, 256, 0, stream>>>(Ctx, Wo, bo, out);
  } else {
    // sequential fallback (bf16 staging buffers)
    __bf16* Qw = (__bf16*)d_ws;
    __bf16* Kw = Qw + e;
    __bf16* Vw = Kw + e;
    __bf16* Ab = Vw + e;
    __bf16* Wb = Ab + e;

    const int actg = (int)(e / 8 / 256);
    const int wg = (int)(w / 8 / 256);
    cvt_f32_bf16<<<actg, 256, 0, stream>>>(query, Ab, (int)(e / 8));
    cvt_f32_bf16<<<wg, 256, 0, stream>>>(Wq, Wb, (int)(w / 8));
    gemm_one<1, __bf16><<<512, 256, 0, stream>>>(Ab, Wb, bq, Qw);
    cvt_f32_bf16<<<actg, 256, 0, stream>>>(key_, Ab, (int)(e / 8));
    cvt_f32_bf16<<<wg, 256, 0, stream>>>(Wk, Wb, (int)(w / 8));
    gemm_one<1, __bf16><<<512, 256, 0, stream>>>(Ab, Wb, bk, Kw);
    cvt_f32_bf16<<<actg, 256, 0, stream>>>(value, Ab, (int)(e / 8));
    cvt_f32_bf16<<<wg, 256, 0, stream>>>(Wv, Wb, (int)(w / 8));
    gemm_one<2, __bf16><<<512, 256, 0, stream>>>(Ab, Wb, bv, Vw);
    flash_attn<__bf16><<<kB * kH * 16, 256, 0, stream>>>(Qw, Kw, Vw, Ab);
    cvt_f32_bf16<<<wg, 256, 0, stream>>>(Wo, Wb, (int)(w / 8));
    gemm_one<0, float><<<512, 256, 0, stream>>>(Ab, Wb, bo, out);
  }
}

// Round 8
// 342.759 us; speedup vs baseline: 1.1549x; 1.1549x over previous
//
#include <hip/hip_runtime.h>
#include <hip/hip_bf16.h>
#include <cstdint>
#include <cstddef>

// B=4, S=2048, D=1024, H=16, DK=64. Device I/O dtype: FLOAT32.
// Internal compute: bf16 MFMA with f32 accumulation.
static constexpr int kB = 4, kS = 2048, kD = 1024, kH = 16, kDK = 64;
static constexpr int kM = kB * kS;

typedef __attribute__((ext_vector_type(8))) __bf16 bf16x8;
typedef __attribute__((ext_vector_type(4))) float f32x4;

#define MFMA_BF16(a, b, c) __builtin_amdgcn_mfma_f32_16x16x32_bf16((a), (b), (c), 0, 0, 0)

#define GLDS16(gp, lp)                                                        \
  __builtin_amdgcn_global_load_lds(                                           \
      (__attribute__((address_space(1))) void*)(gp),                          \
      (__attribute__((address_space(3))) void*)(lp), 16, 0, 0)

// ---------------------------------------------------------------------------
// f32 -> bf16 converters
// ---------------------------------------------------------------------------
__device__ __forceinline__ bf16x8 cvt8(const float* s, int i) {
  const float4 a = ((const float4*)s)[i * 2 + 0];
  const float4 b = ((const float4*)s)[i * 2 + 1];
  bf16x8 o;
  o[0] = (__bf16)a.x; o[1] = (__bf16)a.y; o[2] = (__bf16)a.z; o[3] = (__bf16)a.w;
  o[4] = (__bf16)b.x; o[5] = (__bf16)b.y; o[6] = (__bf16)b.z; o[7] = (__bf16)b.w;
  return o;
}

__global__ __launch_bounds__(256) void cvt_f32_bf16(
    const float* __restrict__ src, __bf16* __restrict__ dst, int n8) {
  const int i = blockIdx.x * 256 + threadIdx.x;
  if (i >= n8) return;
  ((bf16x8*)dst)[i] = cvt8(src, i);
}

// all 7 input tensors in ONE launch: 3x4096 activation blocks + 4x512 weight
__global__ __launch_bounds__(256) void cvt_all(
    const float* __restrict__ q, const float* __restrict__ k,
    const float* __restrict__ v, const float* __restrict__ wq,
    const float* __restrict__ wk, const float* __restrict__ wv,
    const float* __restrict__ wo, __bf16* __restrict__ dq,
    __bf16* __restrict__ dk, __bf16* __restrict__ dv,
    __bf16* __restrict__ dwq, __bf16* __restrict__ dwk,
    __bf16* __restrict__ dwv, __bf16* __restrict__ dwo) {
  int bi = blockIdx.x;
  if (bi < 3 * 4096) {
    const int seg = bi >> 12;
    const int i = (bi & 4095) * 256 + threadIdx.x;
    const float* s = seg == 0 ? q : seg == 1 ? k : v;
    __bf16* d = seg == 0 ? dq : seg == 1 ? dk : dv;
    ((bf16x8*)d)[i] = cvt8(s, i);
  } else {
    bi -= 3 * 4096;
    const int seg = bi >> 9;
    const int i = (bi & 511) * 256 + threadIdx.x;
    const float* s = seg == 0 ? wq : seg == 1 ? wk : seg == 2 ? wv : wo;
    __bf16* d = seg == 0 ? dwq : seg == 1 ? dwk : seg == 2 ? dwv : dwo;
    ((bf16x8*)d)[i] = cvt8(s, i);
  }
}

// ---------------------------------------------------------------------------
// GEMM core: C[M,N] = A[M,K]*W[N,K]^T + bias; 128x128 tile, BK=64
// (proven round-0 structure: 2-barrier K-loop, XOR-granule LDS swizzle,
//  0 bank conflicts, ~86 us / MfmaUtil 24.7 on the QKV launch).
// mode 0: out[m*1024+n] ; mode 1: [b][h][s][dk] ; mode 2: [b][h][dk][s]
// ---------------------------------------------------------------------------
template <typename OutT>
__device__ __forceinline__ void gemm_core(
    const __bf16* __restrict__ A, const __bf16* __restrict__ W,
    const float* __restrict__ bias, OutT* __restrict__ out, int mode, int bid,
    __bf16* As, __bf16* Ws) {
  const int tid = threadIdx.x;
  const int wave = tid >> 6, lane = tid & 63;
  const int col = lane & 15, quad = lane >> 4;
  const int m0 = (bid & 63) * 128;
  const int n0 = (bid >> 6) * 128;
  const int wr = (wave & 1) * 64, wc = (wave >> 1) * 64;

  f32x4 acc[4][4] = {};

  int srow[4], sgo[4];
#pragma unroll
  for (int i = 0; i < 4; ++i) {
    const int s = i * 256 + tid;
    srow[i] = s >> 3;
    sgo[i] = (((s & 7) ^ ((s >> 3) & 7))) * 8;
  }
  const int g0 = ((quad) ^ (col & 7)) * 16;
  const int g1 = ((quad + 4) ^ (col & 7)) * 16;

  for (int k0 = 0; k0 < 1024; k0 += 64) {
#pragma unroll
    for (int i = 0; i < 4; ++i) {
      GLDS16(A + (size_t)(m0 + srow[i]) * 1024 + k0 + sgo[i],
             (char*)As + i * 4096 + wave * 1024);
      GLDS16(W + (size_t)(n0 + srow[i]) * 1024 + k0 + sgo[i],
             (char*)Ws + i * 4096 + wave * 1024);
    }
    __syncthreads();
#pragma unroll
    for (int h = 0; h < 2; ++h) {
      const int go = h ? g1 : g0;
      bf16x8 af[4], wf[4];
#pragma unroll
      for (int t = 0; t < 4; ++t) {
        af[t] = *(const bf16x8*)((const char*)As + (wr + t * 16 + col) * 128 + go);
        wf[t] = *(const bf16x8*)((const char*)Ws + (wc + t * 16 + col) * 128 + go);
      }
#pragma unroll
      for (int rt = 0; rt < 4; ++rt)
#pragma unroll
        for (int ct = 0; ct < 4; ++ct)
          acc[rt][ct] = MFMA_BF16(af[rt], wf[ct], acc[rt][ct]);
    }
    __syncthreads();
  }

#pragma unroll
  for (int ct = 0; ct < 4; ++ct) {
    const int n = n0 + wc + ct * 16 + col;
    const float bb = bias[n];
#pragma unroll
    for (int rt = 0; rt < 4; ++rt) {
#pragma unroll
      for (int r = 0; r < 4; ++r) {
        const int m = m0 + wr + rt * 16 + quad * 4 + r;
        const float v = acc[rt][ct][r] + bb;
        size_t idx;
        if (mode == 0) {
          idx = (size_t)m * 1024 + n;
        } else {
          const int b = m >> 11, s = m & 2047;
          const int h = n >> 6, dk = n & 63;
          if (mode == 1)
            idx = ((size_t)(b * 16 + h) * 2048 + s) * 64 + dk;
          else
            idx = ((size_t)(b * 16 + h) * 64 + dk) * 2048 + s;
        }
        out[idx] = (OutT)v;
      }
    }
  }
}

template <int MODE, typename OutT>
__global__ __launch_bounds__(256) void gemm_one(
    const __bf16* __restrict__ A, const __bf16* __restrict__ W,
    const float* __restrict__ bias, OutT* __restrict__ out) {
  __shared__ __align__(16) __bf16 As[128 * 64];
  __shared__ __align__(16) __bf16 Ws[128 * 64];
  gemm_core<OutT>(A, W, bias, out, MODE, blockIdx.x, As, Ws);
}

// Q/K/V projections fused into one 1536-block launch (round-0 proven)
__global__ __launch_bounds__(256) void gemm_qkv(
    const __bf16* __restrict__ Aq, const __bf16* __restrict__ Ak,
    const __bf16* __restrict__ Av, const __bf16* __restrict__ Wqb,
    const __bf16* __restrict__ Wkb, const __bf16* __restrict__ Wvb,
    const float* __restrict__ bq, const float* __restrict__ bk,
    const float* __restrict__ bv, __bf16* __restrict__ Qw,
    __bf16* __restrict__ Kw, __bf16* __restrict__ Vw) {
  __shared__ __align__(16) __bf16 As[128 * 64];
  __shared__ __align__(16) __bf16 Ws[128 * 64];
  const int seg = blockIdx.x >> 9;
  const int bid = blockIdx.x & 511;
  const __bf16* A = seg == 0 ? Aq : seg == 1 ? Ak : Av;
  const __bf16* W = seg == 0 ? Wqb : seg == 1 ? Wkb : Wvb;
  const float* bias = seg == 0 ? bq : seg == 1 ? bk : bv;
  __bf16* out = seg == 0 ? Qw : seg == 1 ? Kw : Vw;
  gemm_core<__bf16>(A, W, bias, out, seg == 2 ? 2 : 1, bid, As, Ws);
}

// ---------------------------------------------------------------------------
// Causal flash attention — round-5 verified structure.
// Single K/V buffers, counted-vmcnt split staging:
//   entry: vmcnt(2) [K(c) landed]; barrier; QK; barrier -> stage K(c+1);
//   exp/P; vmcnt(2) [V(c) landed]; barrier; PV; barrier -> stage V(c+1).
// Every vmcnt wait precedes a barrier that precedes the cross-wave reads
// (per-wave vmcnt only covers that wave's own GLDS writes).
// LDS = 8192(K) + 8192(V) + 18432(P) = 34816 -> 4 blocks/CU, 1024/1024 slots.
// Block order pair-major: bh = idx&63 -> all 16 pair-blocks of a bh land on
// one XCD (round-robin dispatch), K/V working set/XCD = 8 bh = 4 MB ~ L2;
// longest blocks (pair 0, 32 bodies) launch first.
// ---------------------------------------------------------------------------
__global__ __launch_bounds__(256, 4) void flash_attn(
    const __bf16* __restrict__ Q, const __bf16* __restrict__ K,
    const __bf16* __restrict__ Vt, __bf16* __restrict__ ctx) {
  __shared__ __align__(16) __bf16 Ks[64 * 64];
  __shared__ __align__(16) __bf16 Vs[64 * 64];
  __shared__ __align__(16) __bf16 Pb[4][2][16 * 72];

  const int tid = threadIdx.x;
  const int wave = tid >> 6, lane = tid & 63;
  const int col = lane & 15, quad = lane >> 4;
  const int bh = blockIdx.x & 63;    // pair-major order
  const int pair = blockIdx.x >> 6;
  const int b = bh >> 4, h = bh & 15;
  const int t_lo = pair, t_hi = 31 - pair;
  const int q0f[2] = {t_lo * 64 + wave * 16, t_hi * 64 + wave * 16};

  constexpr float SCL = 0.18033688011112042f;  // (1/8) * log2(e)

  bf16x8 qf[2][2];
#pragma unroll
  for (int f = 0; f < 2; ++f) {
    const __bf16* Qp = Q + ((size_t)bh * kS + q0f[f] + col) * 64 + quad * 8;
    qf[f][0] = *(const bf16x8*)Qp;
    qf[f][1] = *(const bf16x8*)(Qp + 32);
  }

  f32x4 o[2][4] = {};
  f32x4 lacc[2] = {};
  bf16x8 ones;
#pragma unroll
  for (int i = 0; i < 8; ++i) ones[i] = (__bf16)1.0f;

  const __bf16* Kg = K + (size_t)bh * kS * 64;
  const __bf16* Vg = Vt + (size_t)bh * 64 * kS;

  const int row0 = tid >> 3, g0 = (tid & 7) ^ (row0 & 7);
  const int row1 = (256 + tid) >> 3, g1 = (tid & 7) ^ (row1 & 7);

  const int fgoff0 = ((quad) ^ (col & 7)) * 16;
  const int fgoff1 = ((quad + 4) ^ (col & 7)) * 16;
  const int maskbase = wave * 16 + quad * 4;

  __bf16* Pw0 = &Pb[wave][0][0];
  __bf16* Pw1 = &Pb[wave][1][0];
  const __bf16* Pr0 = Pw0 + col * 72 + quad * 8;
  const __bf16* Pr1 = Pw1 + col * 72 + quad * 8;

  auto stageK = [&](int c) {
    char* KsB = (char*)Ks + wave * 1024;
    GLDS16(Kg + (size_t)(c * 64 + row0) * 64 + g0 * 8, KsB);
    GLDS16(Kg + (size_t)(c * 64 + row1) * 64 + g1 * 8, KsB + 4096);
  };
  auto stageV = [&](int c) {
    char* VsB = (char*)Vs + wave * 1024;
    GLDS16(Vg + (size_t)row0 * kS + c * 64 + g0 * 8, VsB);
    GLDS16(Vg + (size_t)row1 * kS + c * 64 + g1 * 8, VsB + 4096);
  };

  auto body = [&](int c, bool lo, bool d0, bool d1, bool stage_next) {
    // K(c) landed? (K issued before V -> vmcnt(2) leaves V(c) in flight)
    asm volatile("s_waitcnt vmcnt(2)" ::: "memory");
    __builtin_amdgcn_s_barrier();
    asm volatile("" ::: "memory");

    f32x4 s[2][4];
#pragma unroll
    for (int kt = 0; kt < 4; ++kt) {
      const char* kp = (const char*)Ks + (kt * 16 + col) * 128;
      const bf16x8 kf0 = *(const bf16x8*)(kp + fgoff0);
      const bf16x8 kf1 = *(const bf16x8*)(kp + fgoff1);
      f32x4 z = {};
      s[1][kt] = MFMA_BF16(qf[1][1], kf1, MFMA_BF16(qf[1][0], kf0, z));
      if (lo) s[0][kt] = MFMA_BF16(qf[0][1], kf1, MFMA_BF16(qf[0][0], kf0, z));
    }

    __builtin_amdgcn_s_barrier();  // K WAR: all waves done reading Ks
    asm volatile("" ::: "memory");
    if (stage_next) stageK(c + 1);

#pragma unroll
    for (int kt = 0; kt < 4; ++kt) {
#pragma unroll
      for (int r = 0; r < 4; ++r) {
        float pv1 = __builtin_amdgcn_exp2f(s[1][kt][r] * SCL);
        if (d1 && (kt * 16 + col > maskbase + r)) pv1 = 0.0f;
        Pw1[(quad * 4 + r) * 72 + kt * 16 + col] = (__bf16)pv1;
        if (lo) {
          float pv0 = __builtin_amdgcn_exp2f(s[0][kt][r] * SCL);
          if (d0 && (kt * 16 + col > maskbase + r)) pv0 = 0.0f;
          Pw0[(quad * 4 + r) * 72 + kt * 16 + col] = (__bf16)pv0;
        }
      }
    }
    __threadfence_block();

    // V(c) landed? (leaves K(c+1) in flight when staged)
    if (stage_next)
      asm volatile("s_waitcnt vmcnt(2)" ::: "memory");
    else
      asm volatile("s_waitcnt vmcnt(0)" ::: "memory");
    __builtin_amdgcn_s_barrier();
    asm volatile("" ::: "memory");

    const bf16x8 pf1a = *(const bf16x8*)Pr1;
    const bf16x8 pf1b = *(const bf16x8*)(Pr1 + 32);
    bf16x8 pf0a = {}, pf0b = {};
    if (lo) {
      pf0a = *(const bf16x8*)Pr0;
      pf0b = *(const bf16x8*)(Pr0 + 32);
    }
#pragma unroll
    for (int dt = 0; dt < 4; ++dt) {
      const char* vp = (const char*)Vs + (dt * 16 + col) * 128;
      const bf16x8 vf0 = *(const bf16x8*)(vp + fgoff0);
      const bf16x8 vf1 = *(const bf16x8*)(vp + fgoff1);
      o[1][dt] = MFMA_BF16(pf1b, vf1, MFMA_BF16(pf1a, vf0, o[1][dt]));
      if (lo) o[0][dt] = MFMA_BF16(pf0b, vf1, MFMA_BF16(pf0a, vf0, o[0][dt]));
    }
    lacc[1] = MFMA_BF16(pf1b, ones, MFMA_BF16(pf1a, ones, lacc[1]));
    if (lo) lacc[0] = MFMA_BF16(pf0b, ones, MFMA_BF16(pf0a, ones, lacc[0]));

    __builtin_amdgcn_s_barrier();  // V WAR: all waves done reading Vs
    asm volatile("" ::: "memory");
    if (stage_next) stageV(c + 1);
  };

  stageK(0);
  stageV(0);
  for (int c = 0; c <= t_lo; ++c) body(c, true, c == t_lo, false, c < t_hi);
  for (int c = t_lo + 1; c <= t_hi; ++c)
    body(c, false, false, c == t_hi, c < t_hi);

#pragma unroll
  for (int f = 0; f < 2; ++f) {
#pragma unroll
    for (int r = 0; r < 4; ++r) {
      const float inv = 1.0f / lacc[f][r];
      const int srow = q0f[f] + quad * 4 + r;
      __bf16* cp = ctx + ((size_t)b * kS + srow) * kD + h * 64 + col;
#pragma unroll
      for (int dt = 0; dt < 4; ++dt)
        cp[dt * 16] = (__bf16)(o[f][dt][r] * inv);
    }
  }
}

// ---------------------------------------------------------------------------
extern "C" void kernel_launch(void* const* d_in, const int* in_sizes, int n_in,
                              void* d_out, int out_size, void* d_ws, size_t ws_size,
                              hipStream_t stream) {
  const float* query = (const float*)d_in[0];
  const float* key_  = (const float*)d_in[1];
  const float* value = (const float*)d_in[2];
  const float* Wq = (const float*)d_in[4];
  const float* bq = (const float*)d_in[5];
  const float* Wk = (const float*)d_in[6];
  const float* bk = (const float*)d_in[7];
  const float* Wv = (const float*)d_in[8];
  const float* bv = (const float*)d_in[9];
  const float* Wo = (const float*)d_in[10];
  const float* bo = (const float*)d_in[11];

  const size_t e = (size_t)kM * kD;       // 8,388,608
  const size_t w = (size_t)kD * kD;       // 1,048,576
  float* out = (float*)d_out;

  const size_t REQ = (6 * e + 4 * w) * sizeof(__bf16);  // ~109 MB

  if (ws_size >= REQ) {
    // fused path
    __bf16* Qw  = (__bf16*)d_ws;
    __bf16* Kw  = Qw + e;
    __bf16* Vw  = Kw + e;     // [B,H,64,S]
    __bf16* Aq  = Vw + e;     // reused as ctx after gemm_qkv
    __bf16* Ak  = Aq + e;
    __bf16* Av  = Ak + e;
    __bf16* Wqb = Av + e;
    __bf16* Wkb = Wqb + w;
    __bf16* Wvb = Wkb + w;
    __bf16* Wob = Wvb + w;

    cvt_all<<<3 * 4096 + 4 * 512, 256, 0, stream>>>(
        query, key_, value, Wq, Wk, Wv, Wo, Aq, Ak, Av, Wqb, Wkb, Wvb, Wob);
    gemm_qkv<<<1536, 256, 0, stream>>>(Aq, Ak, Av, Wqb, Wkb, Wvb, bq, bk, bv,
                                       Qw, Kw, Vw);
    flash_attn<<<kB * kH * 16, 256, 0, stream>>>(Qw, Kw, Vw, Aq);  // ctx -> Aq
    gemm_one<0, float><<<512, 256, 0, stream>>>(Aq, Wob, bo, out);
  } else {
    // sequential fallback
    __bf16* Qw = (__bf16*)d_ws;
    __bf16* Kw = Qw + e;
    __bf16* Vw = Kw + e;
    __bf16* Ab = Vw + e;
    __bf16* Wb = Ab + e;

    const int actg = (int)(e / 8 / 256);
    const int wg = (int)(w / 8 / 256);
    cvt_f32_bf16<<<actg, 256, 0, stream>>>(query, Ab, (int)(e / 8));
    cvt_f32_bf16<<<wg, 256, 0, stream>>>(Wq, Wb, (int)(w / 8));
    gemm_one<1, __bf16><<<512, 256, 0, stream>>>(Ab, Wb, bq, Qw);
    cvt_f32_bf16<<<actg, 256, 0, stream>>>(key_, Ab, (int)(e / 8));
    cvt_f32_bf16<<<wg, 256, 0, stream>>>(Wk, Wb, (int)(w / 8));
    gemm_one<1, __bf16><<<512, 256, 0, stream>>>(Ab, Wb, bk, Kw);
    cvt_f32_bf16<<<actg, 256, 0, stream>>>(value, Ab, (int)(e / 8));
    cvt_f32_bf16<<<wg, 256, 0, stream>>>(Wv, Wb, (int)(w / 8));
    gemm_one<2, __bf16><<<512, 256, 0, stream>>>(Ab, Wb, bv, Vw);
    flash_attn<<<kB * kH * 16, 256, 0, stream>>>(Qw, Kw, Vw, Ab);
    cvt_f32_bf16<<<wg, 256, 0, stream>>>(Wo, Wb, (int)(w / 8));
    gemm_one<0, float><<<512, 256, 0, stream>>>(Ab, Wb, bo, out);
  }
}